// Round 1
// baseline (87.207 us; speedup 1.0000x reference)
//
#include <hip/hip_runtime.h>

#define T_ 16
#define B_ 32
#define N_ 4096
#define NT 20
#define F_ 25
#define H_ 8
#define HID_ 128
#define TBN_ (T_*B_*N_)      // 2097152 points
#define NSEG_ (T_*B_*NT)     // 10240 segments
#define SEGF_ (NT*H_)        // 160 floats per (t,b) pooled row

// Tiny fully-unrolled MLP layer: out = relu(in @ W + b), W is (NI x 8) row-major.
// W/b pointers are wave-uniform kernel args with constant indices -> s_load.
template<int NI>
__device__ __forceinline__ void layer(const float* in,
                                      const float* __restrict__ W,
                                      const float* __restrict__ b,
                                      float* out) {
#pragma unroll
  for (int j = 0; j < H_; j++) {
    float a = b[j];
#pragma unroll
    for (int f = 0; f < NI; f++) a = fmaf(in[f], W[f*H_ + j], a);
    out[j] = fmaxf(a, 0.0f);
  }
}

// Stage A: per-point MLP1 (25->8->8->8, relu, valid mask) + segment max pool 1.
// Optionally stores h3 (fp32 x8) and type/valid byte for stage B.
extern "C" __global__ __launch_bounds__(256)
void kA(const float* __restrict__ pts,
        const float* __restrict__ W1, const float* __restrict__ b1,
        const float* __restrict__ W2, const float* __restrict__ b2,
        const float* __restrict__ W3, const float* __restrict__ b3,
        float* __restrict__ gpool, float* __restrict__ hbuf,
        unsigned char* __restrict__ tbuf, int storeH)
{
  __shared__ float xs[256 * F_];   // 25.6 KB staged points
  __shared__ int lpool[SEGF_];     // per-block (type, j) max pool (nonneg float bits)
  const int tid = threadIdx.x;
  for (int i = tid; i < SEGF_; i += 256) lpool[i] = 0;

  // coalesced global -> LDS staging of 256 points (6400 floats)
  const float* gblk = pts + (size_t)blockIdx.x * (256 * F_);
#pragma unroll
  for (int k = 0; k < F_; k++) xs[tid + k*256] = gblk[tid + k*256];
  __syncthreads();

  float xv[F_];
#pragma unroll
  for (int f = 0; f < F_; f++) xv[f] = xs[tid*F_ + f];   // stride-25: free 2-way bank alias

  // type = argmax over feats 4..23 (first occurrence on ties)
  int ty = 0; float best = xv[4];
#pragma unroll
  for (int k = 1; k < NT; k++) if (xv[4+k] > best) { best = xv[4+k]; ty = k; }
  const bool valid = (xv[F_-1] != 0.0f);

  float h1[H_], h2[H_];
  layer<F_>(xv, W1, b1, h1);
  layer<H_>(h1, W2, b2, h2);
  layer<H_>(h2, W3, b3, h1);           // h1 now holds h3
  if (!valid) {
#pragma unroll
    for (int j = 0; j < H_; j++) h1[j] = 0.0f;
  }

  const int p = blockIdx.x*256 + tid;
  if (storeH) {
    float4* hp = (float4*)(hbuf + (size_t)p * H_);
    hp[0] = make_float4(h1[0], h1[1], h1[2], h1[3]);
    hp[1] = make_float4(h1[4], h1[5], h1[6], h1[7]);
    tbuf[p] = (unsigned char)(ty | (valid ? 0x80 : 0));
  }
  if (valid) {
#pragma unroll
    for (int j = 0; j < H_; j++) atomicMax(&lpool[ty*H_ + j], __float_as_int(h1[j]));
  }
  __syncthreads();

  const int tb = blockIdx.x >> 4;      // 4096/256 = 16 blocks per (t,b)
  int* gp = (int*)gpool + tb*SEGF_;
  for (int i = tid; i < SEGF_; i += 256) {
    int v = lpool[i];
    if (v > 0) atomicMax(&gp[i], v);   // nonneg float bits: int max == float max
  }
}

// Stage B (fast path): read stored h3 + type byte, concat with pooled, MLP2, pool 2.
extern "C" __global__ __launch_bounds__(256)
void kB(const float* __restrict__ hbuf, const unsigned char* __restrict__ tbuf,
        const float* __restrict__ gpool1,
        const float* __restrict__ W4, const float* __restrict__ b4,
        const float* __restrict__ W5, const float* __restrict__ b5,
        const float* __restrict__ W6, const float* __restrict__ b6,
        float* __restrict__ gpool2)
{
  __shared__ float pl[SEGF_];
  __shared__ int lpool[SEGF_];
  const int tid = threadIdx.x;
  const int tb = blockIdx.x >> 4;
  for (int i = tid; i < SEGF_; i += 256) { pl[i] = gpool1[tb*SEGF_ + i]; lpool[i] = 0; }
  __syncthreads();

  const int p = blockIdx.x*256 + tid;
  const unsigned char tv = tbuf[p];
  if (tv & 0x80) {                      // invalid points contribute 0 -> no-op for pool
    const int ty = tv & 0x7f;
    float x16[2*H_];
    const float4* hp = (const float4*)(hbuf + (size_t)p * H_);
    float4 a = hp[0], b = hp[1];
    x16[0]=a.x; x16[1]=a.y; x16[2]=a.z; x16[3]=a.w;
    x16[4]=b.x; x16[5]=b.y; x16[6]=b.z; x16[7]=b.w;
#pragma unroll
    for (int j = 0; j < H_; j++) x16[H_+j] = pl[ty*H_ + j];
    float h1[H_], h2[H_];
    layer<2*H_>(x16, W4, b4, h1);
    layer<H_>(h1, W5, b5, h2);
    layer<H_>(h2, W6, b6, h1);
#pragma unroll
    for (int j = 0; j < H_; j++) atomicMax(&lpool[ty*H_ + j], __float_as_int(h1[j]));
  }
  __syncthreads();

  int* gp = (int*)gpool2 + tb*SEGF_;
  for (int i = tid; i < SEGF_; i += 256) {
    int v = lpool[i];
    if (v > 0) atomicMax(&gp[i], v);
  }
}

// Stage B (fallback if ws too small): recompute MLP1 from points, then MLP2 + pool 2.
extern "C" __global__ __launch_bounds__(256)
void kBrec(const float* __restrict__ pts,
           const float* __restrict__ W1, const float* __restrict__ b1,
           const float* __restrict__ W2, const float* __restrict__ b2,
           const float* __restrict__ W3, const float* __restrict__ b3,
           const float* __restrict__ gpool1,
           const float* __restrict__ W4, const float* __restrict__ b4,
           const float* __restrict__ W5, const float* __restrict__ b5,
           const float* __restrict__ W6, const float* __restrict__ b6,
           float* __restrict__ gpool2)
{
  __shared__ float xs[256 * F_];
  __shared__ float pl[SEGF_];
  __shared__ int lpool[SEGF_];
  const int tid = threadIdx.x;
  const int tb = blockIdx.x >> 4;
  for (int i = tid; i < SEGF_; i += 256) { pl[i] = gpool1[tb*SEGF_ + i]; lpool[i] = 0; }

  const float* gblk = pts + (size_t)blockIdx.x * (256 * F_);
#pragma unroll
  for (int k = 0; k < F_; k++) xs[tid + k*256] = gblk[tid + k*256];
  __syncthreads();

  float xv[F_];
#pragma unroll
  for (int f = 0; f < F_; f++) xv[f] = xs[tid*F_ + f];
  int ty = 0; float best = xv[4];
#pragma unroll
  for (int k = 1; k < NT; k++) if (xv[4+k] > best) { best = xv[4+k]; ty = k; }
  const bool valid = (xv[F_-1] != 0.0f);

  if (valid) {
    float h1[H_], h2[H_];
    layer<F_>(xv, W1, b1, h1);
    layer<H_>(h1, W2, b2, h2);
    layer<H_>(h2, W3, b3, h1);
    float x16[2*H_];
#pragma unroll
    for (int j = 0; j < H_; j++) x16[j] = h1[j];
#pragma unroll
    for (int j = 0; j < H_; j++) x16[H_+j] = pl[ty*H_ + j];
    layer<2*H_>(x16, W4, b4, h1);
    layer<H_>(h1, W5, b5, h2);
    layer<H_>(h2, W6, b6, h1);
#pragma unroll
    for (int j = 0; j < H_; j++) atomicMax(&lpool[ty*H_ + j], __float_as_int(h1[j]));
  }
  __syncthreads();

  int* gp = (int*)gpool2 + tb*SEGF_;
  for (int i = tid; i < SEGF_; i += 256) {
    int v = lpool[i];
    if (v > 0) atomicMax(&gp[i], v);
  }
}

// Stage C: out(512,128) = relu(pooled2(512,160) @ Wout(160,128) + bout)
extern "C" __global__ __launch_bounds__(128)
void kC(const float* __restrict__ gpool2, const float* __restrict__ Wout,
        const float* __restrict__ bout, float* __restrict__ out)
{
  __shared__ float row[SEGF_];
  const int tb = blockIdx.x;
  const int j = threadIdx.x;
  for (int i = j; i < SEGF_; i += 128) row[i] = gpool2[tb*SEGF_ + i];
  __syncthreads();
  float a = bout[j];
#pragma unroll 8
  for (int k = 0; k < SEGF_; k++) a = fmaf(row[k], Wout[k*HID_ + j], a);
  out[tb*HID_ + j] = fmaxf(a, 0.0f);
}

extern "C" void kernel_launch(void* const* d_in, const int* in_sizes, int n_in,
                              void* d_out, int out_size, void* d_ws, size_t ws_size,
                              hipStream_t stream) {
  const float* pts  = (const float*)d_in[0];
  const float* W1   = (const float*)d_in[1];  const float* b1 = (const float*)d_in[2];
  const float* W2   = (const float*)d_in[3];  const float* b2 = (const float*)d_in[4];
  const float* W3   = (const float*)d_in[5];  const float* b3 = (const float*)d_in[6];
  const float* W4   = (const float*)d_in[7];  const float* b4 = (const float*)d_in[8];
  const float* W5   = (const float*)d_in[9];  const float* b5 = (const float*)d_in[10];
  const float* W6   = (const float*)d_in[11]; const float* b6 = (const float*)d_in[12];
  const float* Wout = (const float*)d_in[13]; const float* bout = (const float*)d_in[14];
  float* out = (float*)d_out;

  char* ws = (char*)d_ws;
  const size_t poolBytes = (size_t)NSEG_ * H_ * sizeof(float);   // 327680
  float* gpool1 = (float*)ws;
  float* gpool2 = (float*)(ws + poolBytes);
  const size_t baseBytes = 2 * poolBytes;                         // 16B-aligned
  const size_t hBytes = (size_t)TBN_ * H_ * sizeof(float);        // 64 MB
  const size_t tBytes = (size_t)TBN_;                             // 2 MB
  const bool useH = ws_size >= baseBytes + hBytes + tBytes;
  float* hbuf = (float*)(ws + baseBytes);
  unsigned char* tbuf = (unsigned char*)(ws + baseBytes + hBytes);

  hipMemsetAsync(gpool1, 0, 2 * poolBytes, stream);   // zero bits == 0.0f

  const int nblk = TBN_ / 256;   // 8192
  kA<<<nblk, 256, 0, stream>>>(pts, W1, b1, W2, b2, W3, b3,
                               gpool1, hbuf, tbuf, useH ? 1 : 0);
  if (useH) {
    kB<<<nblk, 256, 0, stream>>>(hbuf, tbuf, gpool1,
                                 W4, b4, W5, b5, W6, b6, gpool2);
  } else {
    kBrec<<<nblk, 256, 0, stream>>>(pts, W1, b1, W2, b2, W3, b3, gpool1,
                                    W4, b4, W5, b5, W6, b6, gpool2);
  }
  kC<<<T_*B_, HID_, 0, stream>>>(gpool2, Wout, bout, out);
}